// Round 1
// 129.790 us; speedup vs baseline: 1.0498x; 1.0498x over previous
//
#include <hip/hip_runtime.h>
#include <hip/hip_bf16.h>

#define N_NODES 50000
#define E_EDGES 800000
#define IN_DIM  128
#define OUT_DIM 64
#define MTILES  (N_NODES / 16)   // 3125, exact
#define NB      196              // coarse dst buckets (dst >> 8)
#define BCAP    6144             // bucket capacity: mean 4096, sd 64 -> +32 sigma
#define OVF_CAP 16384            // overflow list (expected use: 0)
#define NBLK_FC 782              // ceil(3125/4) fc blocks (4 tiles each)
#define NBLK_SA 625              // pass-A blocks (was 256; more tail parallelism)
#define EPA     1280             // 800000/625 edges per pass-A block
#define ITER_A  5                // EPA / 256, uniform compile-time trip count

static_assert(N_NODES % 16 == 0, "16-row MFMA tiles");
static_assert(N_NODES < 65536, "node ids packed in 16 bits");
static_assert(NBLK_SA * EPA == E_EDGES, "pass-A blocks partition edges");
static_assert(EPA == ITER_A * 256, "uniform per-thread trip count");
static_assert(NB * 256 >= N_NODES, "buckets cover dst space");

// ws: harness provides 256 MB; this layout uses 12.1 MB.

typedef __attribute__((ext_vector_type(8))) short bf16x8;
typedef __attribute__((ext_vector_type(4))) float f32x4;
typedef __attribute__((ext_vector_type(8))) unsigned short u16x8;

__device__ __forceinline__ unsigned short f32_to_bf16_rne(float f) {
    unsigned u = __float_as_uint(f);
    return (unsigned short)((u + 0x7FFFu + ((u >> 16) & 1u)) >> 16);
}
__device__ __forceinline__ float bf16_to_f32(unsigned short s) {
    return __uint_as_float(((unsigned)s) << 16);
}

// ---------------------------------------------------------------------------
// K1 (fused): blocks [0, NBLK_FC) = MFMA fc; blocks [NBLK_FC, +NBLK_SA) = pass A.
//
// Pass A (latency-pipelined version): each block owns exactly 1280 edges =
// 5 uniform iterations/thread. All dst+src loads are hoisted into registers
// up front (5-deep MLP, no serial load->atomic chains), reused across the
// histogram and placement passes. Bucket-sort in LDS as before; copy-out
// segments shrink to ~6.5 edges (26 B) -- traded for 2.4x block parallelism.
// ---------------------------------------------------------------------------
__global__ __launch_bounds__(256) void gat_fc_scatter(
    const float* __restrict__ h,
    const float* __restrict__ Wfc,
    const float* __restrict__ bfc,
    const float* __restrict__ Watt,
    const float* __restrict__ batt,
    const int*   __restrict__ adj,
    unsigned short* __restrict__ z16,
    float* __restrict__ s1,
    float* __restrict__ s2,
    int*      __restrict__ gcnt,      // [NB+1] pre-zeroed; [NB] = ovf count
    unsigned* __restrict__ coarse,    // [NB*BCAP]
    unsigned* __restrict__ ovf)
{
    __shared__ short Wlds[OUT_DIM][IN_DIM + 8];   // 17.4 KB (fc blocks)

    if (blockIdx.x < NBLK_FC) {
        // ------------------------------ fc ------------------------------
        for (int i = threadIdx.x; i < OUT_DIM * IN_DIM; i += 256) {
            const int o = i >> 7;            // /128
            const int k = i & 127;
            Wlds[o][k] = (short)f32_to_bf16_rne(Wfc[i]);
        }
        __syncthreads();

        const int lane  = threadIdx.x & 63;
        const int c     = lane & 15;          // A row / B col / C col
        const int q     = lane >> 4;          // quad
        const int mtile = blockIdx.x * 4 + (threadIdx.x >> 6);
        if (mtile >= MTILES) return;
        const int n0 = mtile * 16;

        // B fragments: B[k=t*32+q*8+j][n=f*16+c] = W[f*16+c][t*32+q*8+j]
        bf16x8 B[4][4];
        #pragma unroll
        for (int t = 0; t < 4; ++t)
            #pragma unroll
            for (int f = 0; f < 4; ++f)
                B[t][f] = *(const bf16x8*)&Wlds[f * 16 + c][t * 32 + q * 8];

        f32x4 acc[4] = {{0,0,0,0},{0,0,0,0},{0,0,0,0},{0,0,0,0}};

        const float* arow = h + (size_t)(n0 + c) * IN_DIM + q * 8;
        #pragma unroll
        for (int t = 0; t < 4; ++t) {
            float4 x0 = *(const float4*)(arow + t * 32);
            float4 x1 = *(const float4*)(arow + t * 32 + 4);
            bf16x8 a;
            a[0] = (short)f32_to_bf16_rne(x0.x);
            a[1] = (short)f32_to_bf16_rne(x0.y);
            a[2] = (short)f32_to_bf16_rne(x0.z);
            a[3] = (short)f32_to_bf16_rne(x0.w);
            a[4] = (short)f32_to_bf16_rne(x1.x);
            a[5] = (short)f32_to_bf16_rne(x1.y);
            a[6] = (short)f32_to_bf16_rne(x1.z);
            a[7] = (short)f32_to_bf16_rne(x1.w);
            #pragma unroll
            for (int f = 0; f < 4; ++f)
                acc[f] = __builtin_amdgcn_mfma_f32_16x16x32_bf16(a, B[t][f], acc[f], 0, 0, 0);
        }

        const float batt0 = batt[0];
        float w1c[4], w2c[4], bv[4];
        #pragma unroll
        for (int f = 0; f < 4; ++f) {
            w1c[f] = Watt[f * 16 + c];
            w2c[f] = Watt[OUT_DIM + f * 16 + c];
            bv[f]  = bfc[f * 16 + c];
        }
        float p1[4] = {0,0,0,0}, p2[4] = {0,0,0,0};
        #pragma unroll
        for (int f = 0; f < 4; ++f)
            #pragma unroll
            for (int r = 0; r < 4; ++r) {
                const float v = acc[f][r] + bv[f];
                z16[(size_t)(n0 + q * 4 + r) * OUT_DIM + f * 16 + c] = f32_to_bf16_rne(v);
                p1[r] += v * w1c[f];
                p2[r] += v * w2c[f];
            }
        #pragma unroll
        for (int r = 0; r < 4; ++r) {
            #pragma unroll
            for (int off = 1; off < 16; off <<= 1) {
                p1[r] += __shfl_xor(p1[r], off, 64);
                p2[r] += __shfl_xor(p2[r], off, 64);
            }
            if (c == 0) {
                s1[n0 + q * 4 + r] = p1[r];
                s2[n0 + q * 4 + r] = p2[r] + batt0;   // fold b_att in
            }
        }
    } else {
        // --------------------------- pass A -----------------------------
        __shared__ unsigned el[EPA];                  // 5.1 KB, bucket-sorted
        __shared__ int sof[256];                      // scan workspace
        __shared__ int bexc[NB], lcur[NB], gbase[NB]; // 2.4 KB

        const int k  = blockIdx.x - NBLK_FC;          // 0..624
        const int e0 = k * EPA;
        const int t  = threadIdx.x;

        sof[t] = 0;
        __syncthreads();

        // 0) hoist this thread's 5 dst+src pairs into registers (10 loads
        //    issued together; reused by hist AND placement passes)
        unsigned dv[ITER_A], sv[ITER_A];
        #pragma unroll
        for (int it = 0; it < ITER_A; ++it) {
            dv[it] = (unsigned)adj[E_EDGES + e0 + t + it * 256];
            sv[it] = (unsigned)adj[e0 + t + it * 256];
        }

        // 1) LDS histogram of this block's 1280 dsts
        #pragma unroll
        for (int it = 0; it < ITER_A; ++it)
            atomicAdd(&sof[dv[it] >> 8], 1);
        __syncthreads();
        const int v = sof[t];
        __syncthreads();

        // 2) exclusive scan (Hillis-Steele, 256-wide; entries >= NB are 0)
        sof[t] = v;
        __syncthreads();
        #pragma unroll
        for (int o = 1; o < 256; o <<= 1) {
            const int add = (t >= o) ? sof[t - o] : 0;
            __syncthreads();
            sof[t] += add;
            __syncthreads();
        }
        if (t < NB) {
            const int excl = sof[t] - v;
            bexc[t]  = excl;
            lcur[t]  = excl;
            gbase[t] = atomicAdd(&gcnt[t], v);   // 196 global atomics/block
        }
        __syncthreads();

        // 3) place edges bucket-sorted into LDS (LDS returning cursors,
        //    operands already in registers)
        #pragma unroll
        for (int it = 0; it < ITER_A; ++it) {
            const int b = (int)(dv[it] >> 8);
            const int p = atomicAdd(&lcur[b], 1);
            el[p] = (dv[it] << 16) | sv[it];
        }
        __syncthreads();

        // 4) coalesced copy-out: consecutive i within a bucket -> consecutive
        //    global addresses
        #pragma unroll
        for (int it = 0; it < ITER_A; ++it) {
            const int i = t + it * 256;
            const unsigned packed = el[i];
            const int b = (int)(packed >> 24);           // dst>>8
            const int pin = gbase[b] + (i - bexc[b]);
            if (pin < BCAP) {
                coarse[(size_t)b * BCAP + pin] = packed;
            } else {
                const int o = atomicAdd(&gcnt[NB], 1);
                if (o < OVF_CAP) ovf[o] = packed;
            }
        }
    }
}

// ---------------------------------------------------------------------------
// K2 (pass B): one block per bucket, now 512 threads (8 waves -- this kernel
// runs at the lowest occupancy of the pipeline: 196 blocks on 256 CUs).
// Load+histogram fused into one pass; strided loops unrolled 4x for MLP.
// All returning atomics in LDS.
// ---------------------------------------------------------------------------
__global__ __launch_bounds__(512) void gat_binsort(
    unsigned* __restrict__ coarse,
    const int* __restrict__ gcnt,
    int* __restrict__ start, int* __restrict__ deg)
{
    __shared__ unsigned el[BCAP];                 // 24.6 KB
    __shared__ int hist[256], sof[256], cur[256]; // 3 KB
    const int b  = blockIdx.x;
    const int t  = threadIdx.x;
    const int nb = min(gcnt[b], BCAP);

    if (t < 256) hist[t] = 0;
    __syncthreads();

    // fused load + histogram (one pass over the bucket)
    #pragma unroll 4
    for (int i = t; i < nb; i += 512) {
        const unsigned e = coarse[(size_t)b * BCAP + i];
        el[i] = e;
        atomicAdd(&hist[(e >> 16) & 255], 1);
    }
    __syncthreads();

    const int v = (t < 256) ? hist[t] : 0;
    if (t < 256) sof[t] = v;
    __syncthreads();
    #pragma unroll
    for (int o = 1; o < 256; o <<= 1) {
        const int add = (t >= o && t < 256) ? sof[t - o] : 0;
        __syncthreads();
        if (t < 256) sof[t] += add;
        __syncthreads();
    }
    if (t < 256) {
        const int excl = sof[t] - v;
        cur[t] = excl;
        const int n = b * 256 + t;
        if (n < N_NODES) {
            start[n] = b * BCAP + excl;
            deg[n]   = v;
        }
    }
    __syncthreads();

    #pragma unroll 4
    for (int i = t; i < nb; i += 512) {
        const unsigned e = el[i];
        const int p = atomicAdd(&cur[(e >> 16) & 255], 1);
        coarse[(size_t)b * BCAP + p] = e;
    }
}

// ---------------------------------------------------------------------------
// K3: gather (validated r14/r15 8x8 structure). 8 lanes/edge (ushort8 = 16B
// z load), 8 edge slots -> 8 independent src->z chains; main loop unrolled
// to 16 edges/iter (two independent coarse->s1/z16 chains in flight).
// Reads dst-sorted packed edges via start/deg. No atomics.
// ---------------------------------------------------------------------------
__global__ __launch_bounds__(256) void gat_gather(
    const int* __restrict__ start, const int* __restrict__ deg,
    const unsigned* __restrict__ coarse, const int* __restrict__ gcnt,
    const unsigned* __restrict__ ovf,
    const float* __restrict__ s1, const float* __restrict__ s2,
    const unsigned short* __restrict__ z16,
    float* __restrict__ out)
{
    const int lane = threadIdx.x & 63;
    const int c    = lane & 7;        // feature group: features 8c..8c+7
    const int q    = lane >> 3;       // edge slot 0..7
    const int n    = blockIdx.x * 4 + (threadIdx.x >> 6);
    if (n >= N_NODES) return;

    const int m  = deg[n];
    const int jb = start[n];
    const float s2n = s2[n];                       // includes b_att

    float acc[8] = {0,0,0,0,0,0,0,0};
    int j = 0;
    for (; j + 16 <= m; j += 16) {
        const int srcA = (int)(coarse[jb + j + q] & 0xFFFFu);
        const int srcB = (int)(coarse[jb + j + 8 + q] & 0xFFFFu);
        float aA = s1[srcA] + s2n;
        float aB = s1[srcB] + s2n;
        aA = (aA > 0.f) ? aA : 0.01f * aA;
        aB = (aB > 0.f) ? aB : 0.01f * aB;
        const u16x8 zA = *(const u16x8*)&z16[(size_t)srcA * OUT_DIM + 8 * c];
        const u16x8 zB = *(const u16x8*)&z16[(size_t)srcB * OUT_DIM + 8 * c];
        #pragma unroll
        for (int t = 0; t < 8; ++t) acc[t] += aA * bf16_to_f32(zA[t]);
        #pragma unroll
        for (int t = 0; t < 8; ++t) acc[t] += aB * bf16_to_f32(zB[t]);
    }
    for (; j + 8 <= m; j += 8) {
        const int src = (int)(coarse[jb + j + q] & 0xFFFFu);
        float a = s1[src] + s2n;
        a = (a > 0.f) ? a : 0.01f * a;
        const u16x8 zz = *(const u16x8*)&z16[(size_t)src * OUT_DIM + 8 * c];
        #pragma unroll
        for (int t = 0; t < 8; ++t) acc[t] += a * bf16_to_f32(zz[t]);
    }
    if (q < m - j) {
        const int src = (int)(coarse[jb + j + q] & 0xFFFFu);
        float a = s1[src] + s2n;
        a = (a > 0.f) ? a : 0.01f * a;
        const u16x8 zz = *(const u16x8*)&z16[(size_t)src * OUT_DIM + 8 * c];
        #pragma unroll
        for (int t = 0; t < 8; ++t) acc[t] += a * bf16_to_f32(zz[t]);
    }

    // self-service overflow (expected 0; one scalar load + skip)
    const int novf = min(gcnt[NB], OVF_CAP);
    for (int base = 0; base < novf; base += 8) {
        const int idx = base + q;
        const unsigned packed = (idx < novf) ? ovf[idx] : 0xFFFFFFFFu;
        const bool valid = (idx < novf) && ((packed >> 16) == (unsigned)n);
        const int src = valid ? (int)(packed & 0xFFFFu) : 0;
        float a = s1[src] + s2n;
        a = (a > 0.f) ? a : 0.01f * a;
        a = valid ? a : 0.f;
        const u16x8 zz = *(const u16x8*)&z16[(size_t)src * OUT_DIM + 8 * c];
        #pragma unroll
        for (int t = 0; t < 8; ++t) acc[t] += a * bf16_to_f32(zz[t]);
    }

    // combine the 8 edge slots (slot index in lane bits 3..5)
    #pragma unroll
    for (int t = 0; t < 8; ++t) {
        acc[t] += __shfl_xor(acc[t], 8, 64);
        acc[t] += __shfl_xor(acc[t], 16, 64);
        acc[t] += __shfl_xor(acc[t], 32, 64);
    }

    if (q == 0) {
        float4 lo = make_float4(acc[0], acc[1], acc[2], acc[3]);
        float4 hi = make_float4(acc[4], acc[5], acc[6], acc[7]);
        *(float4*)&out[(size_t)n * OUT_DIM + 8 * c]     = lo;
        *(float4*)&out[(size_t)n * OUT_DIM + 8 * c + 4] = hi;
    }
}

extern "C" void kernel_launch(void* const* d_in, const int* in_sizes, int n_in,
                              void* d_out, int out_size, void* d_ws, size_t ws_size,
                              hipStream_t stream)
{
    const int*   adj  = (const int*)  d_in[0];   // (2, E)
    const float* h    = (const float*)d_in[1];   // (N, 128)
    const float* Wfc  = (const float*)d_in[2];   // (64, 128)
    const float* bfc  = (const float*)d_in[3];   // (64,)
    const float* Watt = (const float*)d_in[4];   // (1, 128)
    const float* batt = (const float*)d_in[5];   // (1,)
    float* out = (float*)d_out;                  // (N, 64)

    // ws layout (12.1 MB): z16[N*64] u16 | s1[N] | s2[N] | start[N] | deg[N]
    // | gcnt[NB+1] ([NB]=ovf count) | ovf[OVF_CAP] u32 | coarse[NB*BCAP] u32
    unsigned short* z16 = (unsigned short*)d_ws;
    float* s1    = (float*)(z16 + (size_t)N_NODES * OUT_DIM);
    float* s2    = s1 + N_NODES;
    int*   start = (int*)(s2 + N_NODES);
    int*   deg   = start + N_NODES;
    int*   gcnt  = deg + N_NODES;
    unsigned* ovf    = (unsigned*)(gcnt + NB + 1);
    unsigned* coarse = ovf + OVF_CAP;

    hipMemsetAsync(gcnt, 0, (NB + 1) * sizeof(int), stream);

    gat_fc_scatter<<<NBLK_FC + NBLK_SA, 256, 0, stream>>>(
        h, Wfc, bfc, Watt, batt, adj, z16, s1, s2, gcnt, coarse, ovf);
    gat_binsort<<<NB, 512, 0, stream>>>(coarse, gcnt, start, deg);
    gat_gather<<<(N_NODES + 3) / 4, 256, 0, stream>>>(
        start, deg, coarse, gcnt, ovf, s1, s2, z16, out);
}